// Round 4
// baseline (120.849 us; speedup 1.0000x reference)
//
#include <hip/hip_runtime.h>
#include <hip/hip_bf16.h>
#include <math.h>

#define B 32
#define S 8
#define FEA 2560
#define T 800
#define NCL 512
#define EMB 256
#define H 8

typedef __attribute__((ext_vector_type(8))) short bf16x8;
typedef __attribute__((ext_vector_type(4))) float f32x4;

// ---------------- Kernel A: pooled via MFMA (+ u blocks riding along) ----------------
// Pool: C(16x16) = A(mask 16xK) * B(x^T Kx16), K=T=800, 25 chunks of 32.
// Explicit 2-buffer register pipeline: compute chunk i while chunk i+1's loads fly.
// u blocks (blockIdx.x==40, b<8): u[n,h] = m[n,:]@U_w[h,:] + U_b[h].

#define LOADP(P, off)                                  \
    P##a0 = *(const float4*)(mr + (off));              \
    P##a1 = *(const float4*)(mr + (off) + 4);          \
    P##b0 = *(const float4*)(xr + (off));              \
    P##b1 = *(const float4*)(xr + (off) + 4);

#define COMP(P) {                                                        \
    union { bf16x8 v; __hip_bfloat162 h[4]; } A_, B_;                    \
    A_.h[0] = __float22bfloat162_rn(make_float2(P##a0.x, P##a0.y));      \
    A_.h[1] = __float22bfloat162_rn(make_float2(P##a0.z, P##a0.w));      \
    A_.h[2] = __float22bfloat162_rn(make_float2(P##a1.x, P##a1.y));      \
    A_.h[3] = __float22bfloat162_rn(make_float2(P##a1.z, P##a1.w));      \
    B_.h[0] = __float22bfloat162_rn(make_float2(P##b0.x, P##b0.y));      \
    B_.h[1] = __float22bfloat162_rn(make_float2(P##b0.z, P##b0.w));      \
    B_.h[2] = __float22bfloat162_rn(make_float2(P##b1.x, P##b1.y));      \
    B_.h[3] = __float22bfloat162_rn(make_float2(P##b1.z, P##b1.w));      \
    acc = __builtin_amdgcn_mfma_f32_16x16x32_bf16(A_.v, B_.v, acc, 0, 0, 0); }

__global__ __launch_bounds__(256) void pool_u_kernel(const float* __restrict__ x,
                                                     const float* __restrict__ mask,
                                                     const float* __restrict__ U_w,
                                                     const float* __restrict__ U_b,
                                                     const float* __restrict__ m,
                                                     float* __restrict__ pooled,
                                                     float* __restrict__ u_out) {
    const int b = blockIdx.y;

    if (blockIdx.x == FEA / 64) {
        // ---- u blocks: 8 blocks, 64 clusters each ----
        if (b >= 8) return;
        const int n  = b * 64 + (threadIdx.x >> 2);
        const int h0 = (threadIdx.x & 3) * 2;
        float a0 = 0.f, a1 = 0.f;
        for (int e = 0; e < EMB; ++e) {
            const float mv = m[n * EMB + e];
            a0 += mv * U_w[h0 * EMB + e];
            a1 += mv * U_w[(h0 + 1) * EMB + e];
        }
        u_out[n * H + h0]     = a0 + U_b[h0];
        u_out[n * H + h0 + 1] = a1 + U_b[h0 + 1];
        return;
    }

    const int wave = threadIdx.x >> 6;
    const int lane = threadIdx.x & 63;
    const int f0   = (blockIdx.x * 4 + wave) * 16;

    const int row = lane & 15;   // A-row (speaker mod 8) / B-col (feature)
    const int kb  = lane >> 4;   // k sub-block 0..3
    const int s   = row & 7;

    const float* xr = x    + ((size_t)b * FEA + (size_t)(f0 + row)) * T + kb * 8;
    const float* mr = mask + ((size_t)(b * S + s)) * T + kb * 8;

    f32x4 acc = {0.f, 0.f, 0.f, 0.f};
    float4 Aa0, Aa1, Ab0, Ab1, Ba0, Ba1, Bb0, Bb1;

    LOADP(A, 0)
    LOADP(B, 32)
    // chunks are 32 floats; 25 chunks: 0..768. Loop computes pairs, loads next pair.
    #pragma unroll 1
    for (int k0 = 64; k0 <= 704; k0 += 64) {
        COMP(A)
        LOADP(A, k0)
        COMP(B)
        LOADP(B, k0 + 32)
    }
    // computed 0..672; A holds 704, B holds 736; chunk 768 remains.
    COMP(A)
    LOADP(A, 768)
    COMP(B)
    COMP(A)

    // C/D layout: col = lane&15, row = (lane>>4)*4 + i. Rows 0..7 = speakers.
    if (lane < 32) {
        #pragma unroll
        for (int i = 0; i < 4; ++i) {
            const int srow = (lane >> 4) * 4 + i;
            pooled[(size_t)(b * S + srow) * FEA + f0 + row] = acc[i];
        }
    }
}

// ---------------- Kernel B: per (b,s): denom, w, gate, e = a @ m ----------------
__global__ __launch_bounds__(256) void wattn_kernel(const float* __restrict__ pooled,
                                                    const float* __restrict__ mask,
                                                    const float* __restrict__ W_w,
                                                    const float* __restrict__ W_b,
                                                    const float* __restrict__ u_in,
                                                    const float* __restrict__ v_w,
                                                    const float* __restrict__ v_b,
                                                    const float* __restrict__ m,
                                                    float* __restrict__ out) {
    __shared__ float u_lds[NCL * H];   // 16 KB
    __shared__ float a_lds[NCL];
    __shared__ float red[256];
    __shared__ float wred[4][8];
    __shared__ float w_sh[H];

    const int bs  = blockIdx.x;
    const int b   = bs >> 3, s = bs & 7;
    const int tid = threadIdx.x;

    for (int i = tid; i < NCL * H; i += 256) u_lds[i] = u_in[i];

    // denom = sum_t mask[b,s,t]
    float p = 0.f;
    for (int t = tid; t < T; t += 256) p += mask[(b * S + s) * T + t];
    red[tid] = p;
    __syncthreads();
    for (int st = 128; st > 0; st >>= 1) {
        if (tid < st) red[tid] += red[tid + st];
        __syncthreads();
    }
    const float inv_d = 1.f / (red[0] + 1e-10f);

    // w[h] = (pooled[b,s,:] * inv_d) @ W_w[h,:] + W_b[h]
    float acc[8];
    #pragma unroll
    for (int h = 0; h < 8; ++h) acc[h] = 0.f;
    for (int f = tid; f < FEA; f += 256) {
        const float xv = pooled[(b * S + s) * FEA + f] * inv_d;
        #pragma unroll
        for (int h = 0; h < 8; ++h) acc[h] += xv * W_w[h * FEA + f];
    }
    const int lane = tid & 63, wave = tid >> 6;
    #pragma unroll
    for (int h = 0; h < 8; ++h) {
        float v = acc[h];
        #pragma unroll
        for (int off = 32; off > 0; off >>= 1) v += __shfl_xor(v, off, 64);
        if (lane == 0) wred[wave][h] = v;
    }
    __syncthreads();
    if (tid < 8)
        w_sh[tid] = wred[0][tid] + wred[1][tid] + wred[2][tid] + wred[3][tid] + W_b[tid];
    __syncthreads();

    // gate
    float vw[8];
    #pragma unroll
    for (int h = 0; h < 8; ++h) vw[h] = v_w[h];
    const float vb = v_b[0];
    for (int n = tid; n < NCL; n += 256) {
        float c = vb;
        #pragma unroll
        for (int h = 0; h < 8; ++h) c += tanhf(w_sh[h] + u_lds[n * H + h]) * vw[h];
        a_lds[n] = 1.f / (1.f + expf(-c));
    }
    __syncthreads();

    // e[emb] = sum_n a[n] * m[n, emb]
    float e = 0.f;
    #pragma unroll 4
    for (int n = 0; n < NCL; ++n) e += a_lds[n] * m[n * EMB + tid];
    out[bs * EMB + tid] = e;
}

extern "C" void kernel_launch(void* const* d_in, const int* in_sizes, int n_in,
                              void* d_out, int out_size, void* d_ws, size_t ws_size,
                              hipStream_t stream) {
    const float* x    = (const float*)d_in[0];
    const float* mask = (const float*)d_in[1];
    const float* W_w  = (const float*)d_in[2];
    const float* W_b  = (const float*)d_in[3];
    const float* U_w  = (const float*)d_in[4];
    const float* U_b  = (const float*)d_in[5];
    const float* v_w  = (const float*)d_in[6];
    const float* v_b  = (const float*)d_in[7];
    const float* m    = (const float*)d_in[8];
    float* out = (float*)d_out;

    float* ws     = (float*)d_ws;
    float* pooled = ws;                       // B*S*FEA floats
    float* u_buf  = ws + B * S * FEA;         // NCL*H floats

    pool_u_kernel<<<dim3(FEA / 64 + 1, B), 256, 0, stream>>>(
        x, mask, U_w, U_b, m, pooled, u_buf);
    wattn_kernel<<<B * S, 256, 0, stream>>>(
        pooled, mask, W_w, W_b, u_buf, v_w, v_b, m, out);
}

// Round 5
// 105.527 us; speedup vs baseline: 1.1452x; 1.1452x over previous
//
#include <hip/hip_runtime.h>
#include <hip/hip_bf16.h>
#include <math.h>

#define B 32
#define S 8
#define FEA 2560
#define T 800
#define NCL 512
#define EMB 256
#define H 8

#define BF 64      // features per block
#define KS 64      // k floats per step
#define NFULL 12   // full K-steps; tail step has 32
#define XROW 72    // shorts per x row in LDS (64 bf16 + 8 pad -> 144B stride, 2-way banks)
#define MROW 808   // shorts per mask row (800 bf16 + 8 pad -> 1616B stride)

typedef __attribute__((ext_vector_type(8))) short bf16x8;
typedef __attribute__((ext_vector_type(4))) float f32x4;

// ---- staging helpers (pool) ----
__device__ __forceinline__ void load_x4(const float* __restrict__ xb_, int f0, int st,
                                        int tid, float4 v[4]) {
    const int kf = st * KS + (tid & 15) * 4;
    const bool ok = (kf < T);
    #pragma unroll
    for (int i = 0; i < 4; ++i) {
        const int row = i * 16 + (tid >> 4);
        v[i] = ok ? *(const float4*)(xb_ + (size_t)(f0 + row) * T + kf)
                  : make_float4(0.f, 0.f, 0.f, 0.f);
    }
}

__device__ __forceinline__ void write_x4(short* __restrict__ dst, int tid, const float4 v[4]) {
    const int c = tid & 15;
    #pragma unroll
    for (int i = 0; i < 4; ++i) {
        const int row = i * 16 + (tid >> 4);
        union { short4 s4; __hip_bfloat162 h[2]; } u;
        u.h[0] = __float22bfloat162_rn(make_float2(v[i].x, v[i].y));
        u.h[1] = __float22bfloat162_rn(make_float2(v[i].z, v[i].w));
        *(short4*)(dst + row * XROW + c * 4) = u.s4;
    }
}

// ---------------- Kernel A: pooled via LDS-staged MFMA (+ u blocks ride along) ----------------
__global__ __launch_bounds__(256) void pool_u_kernel(const float* __restrict__ x,
                                                     const float* __restrict__ mask,
                                                     const float* __restrict__ U_w,
                                                     const float* __restrict__ U_b,
                                                     const float* __restrict__ m,
                                                     float* __restrict__ pooled,
                                                     float* __restrict__ u_out) {
    const int b = blockIdx.y;

    if (blockIdx.x == FEA / BF) {
        // ---- u blocks: 8 blocks, 64 clusters each ----
        if (b >= 8) return;
        const int n  = b * 64 + (threadIdx.x >> 2);
        const int h0 = (threadIdx.x & 3) * 2;
        float a0 = 0.f, a1 = 0.f;
        for (int e = 0; e < EMB; ++e) {
            const float mv = m[n * EMB + e];
            a0 += mv * U_w[h0 * EMB + e];
            a1 += mv * U_w[(h0 + 1) * EMB + e];
        }
        u_out[n * H + h0]     = a0 + U_b[h0];
        u_out[n * H + h0 + 1] = a1 + U_b[h0 + 1];
        return;
    }

    __shared__ short mask_l[S * MROW + 16];
    __shared__ short xls[2 * BF * XROW];

    const int tid = threadIdx.x;
    const int f0  = blockIdx.x * BF;
    const float* xb_ = x + (size_t)b * FEA * T;

    // ---- stage mask[b,:,:] as bf16 (once) ----
    for (int v = tid; v < S * (T / 4); v += 256) {     // 1600 float4's
        const int srow = v / (T / 4), c4 = v % (T / 4);
        const float4 mv = *(const float4*)(mask + ((size_t)(b * S + srow)) * T + c4 * 4);
        union { short4 s4; __hip_bfloat162 h[2]; } u;
        u.h[0] = __float22bfloat162_rn(make_float2(mv.x, mv.y));
        u.h[1] = __float22bfloat162_rn(make_float2(mv.z, mv.w));
        *(short4*)(mask_l + srow * MROW + c4 * 4) = u.s4;
    }

    // ---- stage x step 0 ----
    float4 st_v[4];
    load_x4(xb_, f0, 0, tid, st_v);
    write_x4(xls, tid, st_v);
    __syncthreads();

    const int wave = tid >> 6, lane = tid & 63;
    const int kb = lane >> 4;
    const short* arow  = mask_l + (lane & 7) * MROW + kb * 8;
    const short* xrow0 = xls + (wave * 16 + (lane & 15)) * XROW + kb * 8;

    f32x4 acc = {0.f, 0.f, 0.f, 0.f};

    #pragma unroll 1
    for (int st = 0; st < NFULL; ++st) {
        load_x4(xb_, f0, st + 1, tid, st_v);            // issue next-step loads early
        const short* xr = xrow0 + (st & 1) * BF * XROW;
        bf16x8 a0 = *(const bf16x8*)(arow + st * KS);
        bf16x8 b0 = *(const bf16x8*)(xr);
        acc = __builtin_amdgcn_mfma_f32_16x16x32_bf16(a0, b0, acc, 0, 0, 0);
        bf16x8 a1 = *(const bf16x8*)(arow + st * KS + 32);
        bf16x8 b1 = *(const bf16x8*)(xr + 32);
        acc = __builtin_amdgcn_mfma_f32_16x16x32_bf16(a1, b1, acc, 0, 0, 0);
        write_x4(xls + ((st + 1) & 1) * BF * XROW, tid, st_v);  // vmcnt drain + cvt + write
        __syncthreads();
    }
    // ---- tail: k 768..799, buf 0, single chunk ----
    {
        bf16x8 a0 = *(const bf16x8*)(arow + NFULL * KS);
        bf16x8 b0 = *(const bf16x8*)(xrow0);
        acc = __builtin_amdgcn_mfma_f32_16x16x32_bf16(a0, b0, acc, 0, 0, 0);
    }

    // C/D layout: col = lane&15, row = (lane>>4)*4 + i. Rows 0..7 = speakers.
    if (lane < 32) {
        const int col = lane & 15;
        #pragma unroll
        for (int i = 0; i < 4; ++i) {
            const int srow = (lane >> 4) * 4 + i;
            pooled[(size_t)(b * S + srow) * FEA + f0 + wave * 16 + col] = acc[i];
        }
    }
}

// ---------------- Kernel B: per (b,s): denom, w, gate, e = a @ m ----------------
__global__ __launch_bounds__(256) void wattn_kernel(const float* __restrict__ pooled,
                                                    const float* __restrict__ mask,
                                                    const float* __restrict__ W_w,
                                                    const float* __restrict__ W_b,
                                                    const float* __restrict__ u_in,
                                                    const float* __restrict__ v_w,
                                                    const float* __restrict__ v_b,
                                                    const float* __restrict__ m,
                                                    float* __restrict__ out) {
    __shared__ float u_lds[NCL * H];   // 16 KB
    __shared__ float a_lds[NCL];
    __shared__ float red[256];
    __shared__ float wred[4][8];
    __shared__ float w_sh[H];

    const int bs  = blockIdx.x;
    const int b   = bs >> 3, s = bs & 7;
    const int tid = threadIdx.x;

    for (int i = tid; i < NCL * H; i += 256) u_lds[i] = u_in[i];

    // denom = sum_t mask[b,s,t]
    float p = 0.f;
    for (int t = tid; t < T; t += 256) p += mask[(b * S + s) * T + t];
    red[tid] = p;
    __syncthreads();
    for (int st = 128; st > 0; st >>= 1) {
        if (tid < st) red[tid] += red[tid + st];
        __syncthreads();
    }
    const float inv_d = 1.f / (red[0] + 1e-10f);

    // w[h] = (pooled[b,s,:] * inv_d) @ W_w[h,:] + W_b[h]
    float acc[8];
    #pragma unroll
    for (int h = 0; h < 8; ++h) acc[h] = 0.f;
    for (int f = tid; f < FEA; f += 256) {
        const float xv = pooled[(b * S + s) * FEA + f] * inv_d;
        #pragma unroll
        for (int h = 0; h < 8; ++h) acc[h] += xv * W_w[h * FEA + f];
    }
    const int lane = tid & 63, wave = tid >> 6;
    #pragma unroll
    for (int h = 0; h < 8; ++h) {
        float v = acc[h];
        #pragma unroll
        for (int off = 32; off > 0; off >>= 1) v += __shfl_xor(v, off, 64);
        if (lane == 0) wred[wave][h] = v;
    }
    __syncthreads();
    if (tid < 8)
        w_sh[tid] = wred[0][tid] + wred[1][tid] + wred[2][tid] + wred[3][tid] + W_b[tid];
    __syncthreads();

    // gate
    float vw[8];
    #pragma unroll
    for (int h = 0; h < 8; ++h) vw[h] = v_w[h];
    const float vb = v_b[0];
    for (int n = tid; n < NCL; n += 256) {
        float c = vb;
        #pragma unroll
        for (int h = 0; h < 8; ++h) c += tanhf(w_sh[h] + u_lds[n * H + h]) * vw[h];
        a_lds[n] = 1.f / (1.f + expf(-c));
    }
    __syncthreads();

    // e[emb] = sum_n a[n] * m[n, emb]
    float e = 0.f;
    #pragma unroll 4
    for (int n = 0; n < NCL; ++n) e += a_lds[n] * m[n * EMB + tid];
    out[bs * EMB + tid] = e;
}

extern "C" void kernel_launch(void* const* d_in, const int* in_sizes, int n_in,
                              void* d_out, int out_size, void* d_ws, size_t ws_size,
                              hipStream_t stream) {
    const float* x    = (const float*)d_in[0];
    const float* mask = (const float*)d_in[1];
    const float* W_w  = (const float*)d_in[2];
    const float* W_b  = (const float*)d_in[3];
    const float* U_w  = (const float*)d_in[4];
    const float* U_b  = (const float*)d_in[5];
    const float* v_w  = (const float*)d_in[6];
    const float* v_b  = (const float*)d_in[7];
    const float* m    = (const float*)d_in[8];
    float* out = (float*)d_out;

    float* ws     = (float*)d_ws;
    float* pooled = ws;                       // B*S*FEA floats
    float* u_buf  = ws + B * S * FEA;         // NCL*H floats

    pool_u_kernel<<<dim3(FEA / BF + 1, B), 256, 0, stream>>>(
        x, mask, U_w, U_b, m, pooled, u_buf);
    wattn_kernel<<<B * S, 256, 0, stream>>>(
        pooled, mask, W_w, W_b, u_buf, v_w, v_b, m, out);
}

// Round 6
// 95.130 us; speedup vs baseline: 1.2704x; 1.1093x over previous
//
#include <hip/hip_runtime.h>
#include <hip/hip_bf16.h>
#include <math.h>

#define B 32
#define S 8
#define FEA 2560
#define T 800
#define NCL 512
#define EMB 256
#define H 8

#define BF 64      // features per block
#define KS 64      // k floats per step
#define NFULL 12   // full K-steps; tail step (st=12) has 32 valid k
#define XROW 72    // shorts per x row in LDS (64 bf16 + 8 pad -> 144B stride)
#define MROW 808   // shorts per mask row (800 bf16 + 8 pad)

typedef __attribute__((ext_vector_type(8))) short bf16x8;
typedef __attribute__((ext_vector_type(4))) float f32x4;

// ---- staging helpers (pool) ----
__device__ __forceinline__ void load_x4(const float* __restrict__ xb_, int f0, int st,
                                        int tid, float4 v[4]) {
    const int kf = st * KS + (tid & 15) * 4;
    const bool ok = (kf < T);
    #pragma unroll
    for (int i = 0; i < 4; ++i) {
        const int row = i * 16 + (tid >> 4);
        v[i] = ok ? *(const float4*)(xb_ + (size_t)(f0 + row) * T + kf)
                  : make_float4(0.f, 0.f, 0.f, 0.f);
    }
}

__device__ __forceinline__ void write_x4(short* __restrict__ dst, int tid, const float4 v[4]) {
    const int c = tid & 15;
    #pragma unroll
    for (int i = 0; i < 4; ++i) {
        const int row = i * 16 + (tid >> 4);
        union { short4 s4; __hip_bfloat162 h[2]; } u;
        u.h[0] = __float22bfloat162_rn(make_float2(v[i].x, v[i].y));
        u.h[1] = __float22bfloat162_rn(make_float2(v[i].z, v[i].w));
        *(short4*)(dst + row * XROW + c * 4) = u.s4;
    }
}

#define POOL_STEP(stv, bufofs) {                                           \
    const short* xr_ = xrow0 + (bufofs);                                   \
    bf16x8 a0_ = *(const bf16x8*)(arow + (stv) * KS);                      \
    bf16x8 b0_ = *(const bf16x8*)(xr_);                                    \
    acc = __builtin_amdgcn_mfma_f32_16x16x32_bf16(a0_, b0_, acc, 0, 0, 0); \
    bf16x8 a1_ = *(const bf16x8*)(arow + (stv) * KS + 32);                 \
    bf16x8 b1_ = *(const bf16x8*)(xr_ + 32);                               \
    acc = __builtin_amdgcn_mfma_f32_16x16x32_bf16(a1_, b1_, acc, 0, 0, 0); }

// ---------------- Kernel A: pooled via LDS-staged MFMA, depth-2 pipeline ----------------
__global__ __launch_bounds__(256) void pool_u_kernel(const float* __restrict__ x,
                                                     const float* __restrict__ mask,
                                                     const float* __restrict__ U_w,
                                                     const float* __restrict__ U_b,
                                                     const float* __restrict__ m,
                                                     float* __restrict__ pooled,
                                                     float* __restrict__ u_out) {
    const int b = blockIdx.y;

    if (blockIdx.x == FEA / BF) {
        // ---- u blocks: 8 blocks, 64 clusters each ----
        if (b >= 8) return;
        const int n  = b * 64 + (threadIdx.x >> 2);
        const int h0 = (threadIdx.x & 3) * 2;
        float a0 = 0.f, a1 = 0.f;
        for (int e = 0; e < EMB; ++e) {
            const float mv = m[n * EMB + e];
            a0 += mv * U_w[h0 * EMB + e];
            a1 += mv * U_w[(h0 + 1) * EMB + e];
        }
        u_out[n * H + h0]     = a0 + U_b[h0];
        u_out[n * H + h0 + 1] = a1 + U_b[h0 + 1];
        return;
    }

    __shared__ short mask_l[S * MROW + 16];
    __shared__ short xls[2 * BF * XROW];

    const int tid = threadIdx.x;
    const int f0  = blockIdx.x * BF;
    const float* xb_ = x + (size_t)b * FEA * T;

    float4 bufP[4], bufN[4];

    // ---- prologue: issue step-0 loads, stage mask while they fly ----
    load_x4(xb_, f0, 0, tid, bufN);

    for (int v = tid; v < S * (T / 4); v += 256) {     // mask[b,:,:] -> bf16 LDS
        const int srow = v / (T / 4), c4 = v % (T / 4);
        const float4 mv = *(const float4*)(mask + ((size_t)(b * S + srow)) * T + c4 * 4);
        union { short4 s4; __hip_bfloat162 h[2]; } u;
        u.h[0] = __float22bfloat162_rn(make_float2(mv.x, mv.y));
        u.h[1] = __float22bfloat162_rn(make_float2(mv.z, mv.w));
        *(short4*)(mask_l + srow * MROW + c4 * 4) = u.s4;
    }

    write_x4(xls, tid, bufN);          // LDS buf0 = step 0
    load_x4(xb_, f0, 1, tid, bufP);    // pending step 1
    __syncthreads();

    const int wave = tid >> 6, lane = tid & 63;
    const int kb = lane >> 4;
    const short* arow  = mask_l + (lane & 7) * MROW + kb * 8;
    const short* xrow0 = xls + (wave * 16 + (lane & 15)) * XROW + kb * 8;

    f32x4 acc = {0.f, 0.f, 0.f, 0.f};

    // ---- main loop: 2x unrolled, depth-2 (write lags load by a full iteration) ----
    #pragma unroll 1
    for (int st = 0; st < NFULL; st += 2) {
        // even: LDS buf0 holds step st; bufP holds step st+1
        load_x4(xb_, f0, st + 2, tid, bufN);
        POOL_STEP(st, 0)
        write_x4(xls + BF * XROW, tid, bufP);     // step st+1 -> buf1
        __syncthreads();
        // odd: LDS buf1 holds step st+1; bufN holds step st+2
        load_x4(xb_, f0, st + 3, tid, bufP);      // st+3==13 -> guarded zeros
        POOL_STEP(st + 1, BF * XROW)
        write_x4(xls, tid, bufN);                 // step st+2 -> buf0
        __syncthreads();
    }
    // ---- tail: buf0 holds step 12 (k 768..799 valid), single chunk ----
    {
        bf16x8 a0_ = *(const bf16x8*)(arow + NFULL * KS);
        bf16x8 b0_ = *(const bf16x8*)(xrow0);
        acc = __builtin_amdgcn_mfma_f32_16x16x32_bf16(a0_, b0_, acc, 0, 0, 0);
    }

    // C/D layout: col = lane&15, row = (lane>>4)*4 + i. Rows 0..7 = speakers.
    if (lane < 32) {
        const int col = lane & 15;
        #pragma unroll
        for (int i = 0; i < 4; ++i) {
            const int srow = (lane >> 4) * 4 + i;
            pooled[(size_t)(b * S + srow) * FEA + f0 + wave * 16 + col] = acc[i];
        }
    }
}

// ---------------- Kernel B: per (b,s): denom, w, gate, e = a @ m ----------------
__global__ __launch_bounds__(256) void wattn_kernel(const float* __restrict__ pooled,
                                                    const float* __restrict__ mask,
                                                    const float* __restrict__ W_w,
                                                    const float* __restrict__ W_b,
                                                    const float* __restrict__ u_in,
                                                    const float* __restrict__ v_w,
                                                    const float* __restrict__ v_b,
                                                    const float* __restrict__ m,
                                                    float* __restrict__ out) {
    __shared__ float u_lds[NCL * H];   // 16 KB
    __shared__ float a_lds[NCL];
    __shared__ float red[256];
    __shared__ float wred[4][8];
    __shared__ float w_sh[H];

    const int bs  = blockIdx.x;
    const int b   = bs >> 3, s = bs & 7;
    const int tid = threadIdx.x;

    for (int i = tid; i < NCL * H; i += 256) u_lds[i] = u_in[i];

    // denom = sum_t mask[b,s,t]
    float p = 0.f;
    for (int t = tid; t < T; t += 256) p += mask[(b * S + s) * T + t];
    red[tid] = p;
    __syncthreads();
    for (int st = 128; st > 0; st >>= 1) {
        if (tid < st) red[tid] += red[tid + st];
        __syncthreads();
    }
    const float inv_d = 1.f / (red[0] + 1e-10f);

    // w[h] = (pooled[b,s,:] * inv_d) @ W_w[h,:] + W_b[h]
    float acc[8];
    #pragma unroll
    for (int h = 0; h < 8; ++h) acc[h] = 0.f;
    for (int f = tid; f < FEA; f += 256) {
        const float xv = pooled[(b * S + s) * FEA + f] * inv_d;
        #pragma unroll
        for (int h = 0; h < 8; ++h) acc[h] += xv * W_w[h * FEA + f];
    }
    const int lane = tid & 63, wave = tid >> 6;
    #pragma unroll
    for (int h = 0; h < 8; ++h) {
        float v = acc[h];
        #pragma unroll
        for (int off = 32; off > 0; off >>= 1) v += __shfl_xor(v, off, 64);
        if (lane == 0) wred[wave][h] = v;
    }
    __syncthreads();
    if (tid < 8)
        w_sh[tid] = wred[0][tid] + wred[1][tid] + wred[2][tid] + wred[3][tid] + W_b[tid];
    __syncthreads();

    // gate
    float vw[8];
    #pragma unroll
    for (int h = 0; h < 8; ++h) vw[h] = v_w[h];
    const float vb = v_b[0];
    for (int n = tid; n < NCL; n += 256) {
        float c = vb;
        #pragma unroll
        for (int h = 0; h < 8; ++h) c += tanhf(w_sh[h] + u_lds[n * H + h]) * vw[h];
        a_lds[n] = 1.f / (1.f + expf(-c));
    }
    __syncthreads();

    // e[emb] = sum_n a[n] * m[n, emb]
    float e = 0.f;
    #pragma unroll 4
    for (int n = 0; n < NCL; ++n) e += a_lds[n] * m[n * EMB + tid];
    out[bs * EMB + tid] = e;
}

extern "C" void kernel_launch(void* const* d_in, const int* in_sizes, int n_in,
                              void* d_out, int out_size, void* d_ws, size_t ws_size,
                              hipStream_t stream) {
    const float* x    = (const float*)d_in[0];
    const float* mask = (const float*)d_in[1];
    const float* W_w  = (const float*)d_in[2];
    const float* W_b  = (const float*)d_in[3];
    const float* U_w  = (const float*)d_in[4];
    const float* U_b  = (const float*)d_in[5];
    const float* v_w  = (const float*)d_in[6];
    const float* v_b  = (const float*)d_in[7];
    const float* m    = (const float*)d_in[8];
    float* out = (float*)d_out;

    float* ws     = (float*)d_ws;
    float* pooled = ws;                       // B*S*FEA floats
    float* u_buf  = ws + B * S * FEA;         // NCL*H floats

    pool_u_kernel<<<dim3(FEA / BF + 1, B), 256, 0, stream>>>(
        x, mask, U_w, U_b, m, pooled, u_buf);
    wattn_kernel<<<B * S, 256, 0, stream>>>(
        pooled, mask, W_w, W_b, u_buf, v_w, v_b, m, out);
}

// Round 7
// 94.555 us; speedup vs baseline: 1.2781x; 1.0061x over previous
//
#include <hip/hip_runtime.h>
#include <hip/hip_bf16.h>
#include <math.h>

#define B 32
#define S 8
#define FEA 2560
#define T 800
#define TH 400     // T per half (grid.z = 2)
#define NCL 512
#define EMB 256
#define H 8

#define BF 64      // features per block
#define KS 64      // k floats per step
#define NF 6       // full K-steps per half; tail step (6) has 16 valid k
#define XROW 72    // shorts per x row in LDS (64 bf16 + 8 pad -> 144B stride)
#define MROW 416   // shorts per mask row (400 bf16 + 16 zero-pad)

typedef __attribute__((ext_vector_type(8))) short bf16x8;
typedef __attribute__((ext_vector_type(4))) float f32x4;

// ---- staging helpers (pool) ----
__device__ __forceinline__ void load_x4(const float* __restrict__ xh, int f0, int st,
                                        int tid, float4 v[4]) {
    const int kf = st * KS + (tid & 15) * 4;   // local k (0..TH-1 valid)
    const bool ok = (kf < TH);
    #pragma unroll
    for (int i = 0; i < 4; ++i) {
        const int row = i * 16 + (tid >> 4);
        v[i] = ok ? *(const float4*)(xh + (size_t)(f0 + row) * T + kf)
                  : make_float4(0.f, 0.f, 0.f, 0.f);
    }
}

__device__ __forceinline__ void write_x4(short* __restrict__ dst, int tid, const float4 v[4]) {
    const int c = tid & 15;
    #pragma unroll
    for (int i = 0; i < 4; ++i) {
        const int row = i * 16 + (tid >> 4);
        union { short4 s4; __hip_bfloat162 h[2]; } u;
        u.h[0] = __float22bfloat162_rn(make_float2(v[i].x, v[i].y));
        u.h[1] = __float22bfloat162_rn(make_float2(v[i].z, v[i].w));
        *(short4*)(dst + row * XROW + c * 4) = u.s4;
    }
}

#define POOL_STEP(stv, bufofs) {                                           \
    const short* xr_ = xrow0 + (bufofs);                                   \
    bf16x8 a0_ = *(const bf16x8*)(arow + (stv) * KS);                      \
    bf16x8 b0_ = *(const bf16x8*)(xr_);                                    \
    acc = __builtin_amdgcn_mfma_f32_16x16x32_bf16(a0_, b0_, acc, 0, 0, 0); \
    bf16x8 a1_ = *(const bf16x8*)(arow + (stv) * KS + 32);                 \
    bf16x8 b1_ = *(const bf16x8*)(xr_ + 32);                               \
    acc = __builtin_amdgcn_mfma_f32_16x16x32_bf16(a1_, b1_, acc, 0, 0, 0); }

// ---------------- Kernel A: pooled partials via MFMA, symmetric depth-2 pipeline ----------------
// grid (41, B, 2); x==40,z==0,y<8 -> u blocks. Else: half th of K for feature tile f0.
__global__ __launch_bounds__(256, 6) void pool_u_kernel(const float* __restrict__ x,
                                                        const float* __restrict__ mask,
                                                        const float* __restrict__ U_w,
                                                        const float* __restrict__ U_b,
                                                        const float* __restrict__ m,
                                                        float* __restrict__ pooled_p,
                                                        float* __restrict__ u_out) {
    const int b  = blockIdx.y;
    const int th = blockIdx.z;

    if (blockIdx.x == FEA / BF) {
        if (th != 0 || b >= 8) return;
        const int n  = b * 64 + (threadIdx.x >> 2);
        const int h0 = (threadIdx.x & 3) * 2;
        float a0 = 0.f, a1 = 0.f;
        for (int e = 0; e < EMB; ++e) {
            const float mv = m[n * EMB + e];
            a0 += mv * U_w[h0 * EMB + e];
            a1 += mv * U_w[(h0 + 1) * EMB + e];
        }
        u_out[n * H + h0]     = a0 + U_b[h0];
        u_out[n * H + h0 + 1] = a1 + U_b[h0 + 1];
        return;
    }

    __shared__ short mask_l[S * MROW];        // 6656 B
    __shared__ short xls[2 * BF * XROW];      // 18432 B

    const int tid = threadIdx.x;
    const int f0  = blockIdx.x * BF;
    const float* xh = x + (size_t)b * FEA * T + th * TH;        // half-offset base
    const float* mh = mask + ((size_t)b * S) * T + th * TH;

    float4 R0[4], R1[4];

    // ---- prologue ----
    load_x4(xh, f0, 0, tid, R0);
    load_x4(xh, f0, 1, tid, R1);

    // stage mask rows (TH cols) as bf16 while loads fly
    for (int v = tid; v < S * (TH / 4); v += 256) {    // 800 float4
        const int srow = v / (TH / 4), c4 = v % (TH / 4);
        const float4 mv = *(const float4*)(mh + (size_t)srow * T + c4 * 4);
        union { short4 s4; __hip_bfloat162 h[2]; } u;
        u.h[0] = __float22bfloat162_rn(make_float2(mv.x, mv.y));
        u.h[1] = __float22bfloat162_rn(make_float2(mv.z, mv.w));
        *(short4*)(mask_l + srow * MROW + c4 * 4) = u.s4;
    }
    if (tid < 32) {    // zero pad cols 400..415 (tail MFMA reads them)
        const int srow = tid >> 2, c4 = tid & 3;
        *(short4*)(mask_l + srow * MROW + TH + c4 * 4) = make_short4(0, 0, 0, 0);
    }

    write_x4(xls, tid, R0);                 // step 0 -> LDS0 (waits R0)
    load_x4(xh, f0, 2, tid, R0);
    write_x4(xls + BF * XROW, tid, R1);     // step 1 -> LDS1 (waits R1)
    load_x4(xh, f0, 3, tid, R1);
    __syncthreads();

    const int wave = tid >> 6, lane = tid & 63;
    const int kb = lane >> 4;
    const short* arow  = mask_l + (lane & 7) * MROW + kb * 8;
    const short* xrow0 = xls + (wave * 16 + (lane & 15)) * XROW + kb * 8;

    f32x4 acc = {0.f, 0.f, 0.f, 0.f};

    // ---- main loop: steps 0..3 over 2 iterations; both writes lag loads by a full iter ----
    #pragma unroll 1
    for (int st = 0; st < 4; st += 2) {
        POOL_STEP(st, 0)
        __syncthreads();                          // LDS0 reads done
        write_x4(xls, tid, R0);                   // step st+2 -> LDS0
        load_x4(xh, f0, st + 4, tid, R0);         // guarded zeros past NF
        POOL_STEP(st + 1, BF * XROW)
        __syncthreads();                          // LDS1 reads done; orders LDS0 write vs next read
        write_x4(xls + BF * XROW, tid, R1);       // step st+3 -> LDS1
        load_x4(xh, f0, st + 5, tid, R1);
    }
    // ---- epilogue: LDS0=4, LDS1=5, R0=step 6 (tail data) ----
    POOL_STEP(4, 0)
    __syncthreads();
    write_x4(xls, tid, R0);                       // step 6 -> LDS0
    POOL_STEP(5, BF * XROW)
    __syncthreads();                              // orders step-6 write before tail read
    {   // tail: k local 384..415 (valid 384..399; rest zeros in both A and B)
        bf16x8 a0_ = *(const bf16x8*)(arow + NF * KS);
        bf16x8 b0_ = *(const bf16x8*)(xrow0);
        acc = __builtin_amdgcn_mfma_f32_16x16x32_bf16(a0_, b0_, acc, 0, 0, 0);
    }

    // C/D layout: col = lane&15, row = (lane>>4)*4 + i. Rows 0..7 = speakers.
    if (lane < 32) {
        const int col = lane & 15;
        #pragma unroll
        for (int i = 0; i < 4; ++i) {
            const int srow = (lane >> 4) * 4 + i;
            pooled_p[((size_t)th * B * S + (size_t)(b * S + srow)) * FEA + f0 + wave * 16 + col]
                = acc[i];
        }
    }
}

// ---------------- Kernel B: per (b,s): denom, w, gate, e = a @ m ----------------
__global__ __launch_bounds__(256) void wattn_kernel(const float* __restrict__ pooled_p,
                                                    const float* __restrict__ mask,
                                                    const float* __restrict__ W_w,
                                                    const float* __restrict__ W_b,
                                                    const float* __restrict__ u_in,
                                                    const float* __restrict__ v_w,
                                                    const float* __restrict__ v_b,
                                                    const float* __restrict__ m,
                                                    float* __restrict__ out) {
    __shared__ float u_lds[NCL * H];   // 16 KB
    __shared__ float a_lds[NCL];
    __shared__ float red[256];
    __shared__ float wred[4][8];
    __shared__ float w_sh[H];

    const int bs  = blockIdx.x;
    const int b   = bs >> 3, s = bs & 7;
    const int tid = threadIdx.x;

    for (int i = tid; i < NCL * H; i += 256) u_lds[i] = u_in[i];

    // denom = sum_t mask[b,s,t]
    float p = 0.f;
    for (int t = tid; t < T; t += 256) p += mask[(b * S + s) * T + t];
    red[tid] = p;
    __syncthreads();
    for (int st = 128; st > 0; st >>= 1) {
        if (tid < st) red[tid] += red[tid + st];
        __syncthreads();
    }
    const float inv_d = 1.f / (red[0] + 1e-10f);

    // w[h] = (pooled[b,s,:] * inv_d) @ W_w[h,:] + W_b[h]
    float acc[8];
    #pragma unroll
    for (int h = 0; h < 8; ++h) acc[h] = 0.f;
    for (int f = tid; f < FEA; f += 256) {
        const float xv = (pooled_p[(size_t)bs * FEA + f]
                        + pooled_p[(size_t)(B * S + bs) * FEA + f]) * inv_d;
        #pragma unroll
        for (int h = 0; h < 8; ++h) acc[h] += xv * W_w[h * FEA + f];
    }
    const int lane = tid & 63, wave = tid >> 6;
    #pragma unroll
    for (int h = 0; h < 8; ++h) {
        float v = acc[h];
        #pragma unroll
        for (int off = 32; off > 0; off >>= 1) v += __shfl_xor(v, off, 64);
        if (lane == 0) wred[wave][h] = v;
    }
    __syncthreads();
    if (tid < 8)
        w_sh[tid] = wred[0][tid] + wred[1][tid] + wred[2][tid] + wred[3][tid] + W_b[tid];
    __syncthreads();

    // gate
    float vw[8];
    #pragma unroll
    for (int h = 0; h < 8; ++h) vw[h] = v_w[h];
    const float vb = v_b[0];
    for (int n = tid; n < NCL; n += 256) {
        float c = vb;
        #pragma unroll
        for (int h = 0; h < 8; ++h) c += tanhf(w_sh[h] + u_lds[n * H + h]) * vw[h];
        a_lds[n] = 1.f / (1.f + expf(-c));
    }
    __syncthreads();

    // e[emb] = sum_n a[n] * m[n, emb]
    float e = 0.f;
    #pragma unroll 4
    for (int n = 0; n < NCL; ++n) e += a_lds[n] * m[n * EMB + tid];
    out[bs * EMB + tid] = e;
}

extern "C" void kernel_launch(void* const* d_in, const int* in_sizes, int n_in,
                              void* d_out, int out_size, void* d_ws, size_t ws_size,
                              hipStream_t stream) {
    const float* x    = (const float*)d_in[0];
    const float* mask = (const float*)d_in[1];
    const float* W_w  = (const float*)d_in[2];
    const float* W_b  = (const float*)d_in[3];
    const float* U_w  = (const float*)d_in[4];
    const float* U_b  = (const float*)d_in[5];
    const float* v_w  = (const float*)d_in[6];
    const float* v_b  = (const float*)d_in[7];
    const float* m    = (const float*)d_in[8];
    float* out = (float*)d_out;

    float* ws       = (float*)d_ws;
    float* pooled_p = ws;                         // 2 * B*S*FEA floats (partials)
    float* u_buf    = ws + 2 * B * S * FEA;       // NCL*H floats

    pool_u_kernel<<<dim3(FEA / BF + 1, B, 2), 256, 0, stream>>>(
        x, mask, U_w, U_b, m, pooled_p, u_buf);
    wattn_kernel<<<B * S, 256, 0, stream>>>(
        pooled_p, mask, W_w, W_b, u_buf, v_w, v_b, m, out);
}

// Round 8
// 93.821 us; speedup vs baseline: 1.2881x; 1.0078x over previous
//
#include <hip/hip_runtime.h>
#include <hip/hip_bf16.h>
#include <math.h>

#define B 32
#define S 8
#define FEA 2560
#define T 800
#define TH 400     // T per half (grid.z = 2)
#define NCL 512
#define EMB 256
#define H 8

#define BF 64      // features per block (16 per wave)
#define KS 64      // k floats per step
#define NF 6       // full K-steps per half; tail step (6) has 16 valid k
#define XROW 72    // shorts per x row in LDS (64 bf16 + 8 pad -> 144B stride)
#define MROW 424   // shorts per mask row (400 bf16 + pad; 848B stride -> conflict-free)
#define WBUF (16 * XROW)   // shorts per wave x-buffer

typedef __attribute__((ext_vector_type(8))) short bf16x8;
typedef __attribute__((ext_vector_type(4))) float f32x4;

// ---- wave-private staging helpers ----
// xw = &x[b][f0 + wave*16][th*TH]; lane covers 4 rows x 16 float4-chunks per call.
__device__ __forceinline__ void load_xw(const float* __restrict__ xw, int st,
                                        int lane, float4 v[4]) {
    const int kf = st * KS + (lane & 15) * 4;   // local k
    const bool ok = (kf < TH);
    #pragma unroll
    for (int i = 0; i < 4; ++i) {
        const int row = i * 4 + (lane >> 4);
        v[i] = ok ? *(const float4*)(xw + (size_t)row * T + kf)
                  : make_float4(0.f, 0.f, 0.f, 0.f);
    }
}

__device__ __forceinline__ void write_xw(short* __restrict__ dst, int lane, const float4 v[4]) {
    const int c = lane & 15;
    #pragma unroll
    for (int i = 0; i < 4; ++i) {
        const int row = i * 4 + (lane >> 4);
        union { short4 s4; __hip_bfloat162 h[2]; } u;
        u.h[0] = __float22bfloat162_rn(make_float2(v[i].x, v[i].y));
        u.h[1] = __float22bfloat162_rn(make_float2(v[i].z, v[i].w));
        *(short4*)(dst + row * XROW + c * 4) = u.s4;
    }
}

#define POOL_STEP(stv, bufofs) {                                           \
    const short* xr_ = xrow0 + (bufofs);                                   \
    bf16x8 a0_ = *(const bf16x8*)(arow + (stv) * KS);                      \
    bf16x8 b0_ = *(const bf16x8*)(xr_);                                    \
    acc = __builtin_amdgcn_mfma_f32_16x16x32_bf16(a0_, b0_, acc, 0, 0, 0); \
    bf16x8 a1_ = *(const bf16x8*)(arow + (stv) * KS + 32);                 \
    bf16x8 b1_ = *(const bf16x8*)(xr_ + 32);                               \
    acc = __builtin_amdgcn_mfma_f32_16x16x32_bf16(a1_, b1_, acc, 0, 0, 0); }

// ---------------- Kernel A: pooled partials via MFMA, wave-private barrier-free pipeline ----------------
// grid (41, B, 2); x==40,z==0,y<8 -> u blocks.
__global__ __launch_bounds__(256, 6) void pool_u_kernel(const float* __restrict__ x,
                                                        const float* __restrict__ mask,
                                                        const float* __restrict__ U_w,
                                                        const float* __restrict__ U_b,
                                                        const float* __restrict__ m,
                                                        float* __restrict__ pooled_p,
                                                        float* __restrict__ u_out) {
    const int b  = blockIdx.y;
    const int th = blockIdx.z;

    if (blockIdx.x == FEA / BF) {
        if (th != 0 || b >= 8) return;
        const int n  = b * 64 + (threadIdx.x >> 2);
        const int h0 = (threadIdx.x & 3) * 2;
        float a0 = 0.f, a1 = 0.f;
        for (int e = 0; e < EMB; ++e) {
            const float mv = m[n * EMB + e];
            a0 += mv * U_w[h0 * EMB + e];
            a1 += mv * U_w[(h0 + 1) * EMB + e];
        }
        u_out[n * H + h0]     = a0 + U_b[h0];
        u_out[n * H + h0 + 1] = a1 + U_b[h0 + 1];
        return;
    }

    __shared__ short mask_l[S * MROW];            // 6784 B, shared, read-only after barrier
    __shared__ short xls[4 * 2 * WBUF];           // 18432 B, wave-private double buffers

    const int tid  = threadIdx.x;
    const int wave = tid >> 6, lane = tid & 63;
    const int f0   = blockIdx.x * BF;

    const float* xw = x + ((size_t)b * FEA + f0 + wave * 16) * T + th * TH;
    const float* mh = mask + ((size_t)b * S) * T + th * TH;
    short* wbuf = xls + wave * 2 * WBUF;

    float4 R0[4], R1[4];

    // ---- prologue: issue first two x steps, stage mask while they fly ----
    load_xw(xw, 0, lane, R0);
    load_xw(xw, 1, lane, R1);

    for (int v = tid; v < S * (TH / 4); v += 256) {    // 800 float4
        const int srow = v / (TH / 4), c4 = v % (TH / 4);
        const float4 mv = *(const float4*)(mh + (size_t)srow * T + c4 * 4);
        union { short4 s4; __hip_bfloat162 h[2]; } u;
        u.h[0] = __float22bfloat162_rn(make_float2(mv.x, mv.y));
        u.h[1] = __float22bfloat162_rn(make_float2(mv.z, mv.w));
        *(short4*)(mask_l + srow * MROW + c4 * 4) = u.s4;
    }
    if (tid < S * 6) {    // zero-pad cols 400..423 (tail MFMA reads 400..415)
        const int srow = tid / 6, c4 = tid % 6;
        *(short4*)(mask_l + srow * MROW + TH + c4 * 4) = make_short4(0, 0, 0, 0);
    }
    __syncthreads();      // the ONLY barrier: mask_l visible to all waves

    write_xw(wbuf, lane, R0);                // step 0 -> buf0
    load_xw(xw, 2, lane, R0);
    write_xw(wbuf + WBUF, lane, R1);         // step 1 -> buf1
    load_xw(xw, 3, lane, R1);

    const int kb = lane >> 4;
    const short* arow  = mask_l + (lane & 7) * MROW + kb * 8;
    const short* xrow0 = wbuf + (lane & 15) * XROW + kb * 8;

    f32x4 acc = {0.f, 0.f, 0.f, 0.f};

    // ---- main loop: barrier-free, depth-2 (each write's vmcnt-wait lags its load by a full iter) ----
    #pragma unroll 1
    for (int st = 0; st < 4; st += 2) {
        POOL_STEP(st, 0)
        write_xw(wbuf, lane, R0);            // step st+2 -> buf0 (same-wave ds order vs reads above)
        load_xw(xw, st + 4, lane, R0);
        POOL_STEP(st + 1, WBUF)
        write_xw(wbuf + WBUF, lane, R1);     // step st+3 -> buf1
        load_xw(xw, st + 5, lane, R1);       // st+5 >= 7 -> guarded zeros
    }
    // ---- epilogue: buf0=step4, buf1=step5, R0=step6 ----
    POOL_STEP(4, 0)
    write_xw(wbuf, lane, R0);                // step 6 -> buf0
    POOL_STEP(5, WBUF)
    {   // tail: local k 384..415 (valid 384..399; zeros beyond in both A and B)
        bf16x8 a0_ = *(const bf16x8*)(arow + NF * KS);
        bf16x8 b0_ = *(const bf16x8*)(xrow0);
        acc = __builtin_amdgcn_mfma_f32_16x16x32_bf16(a0_, b0_, acc, 0, 0, 0);
    }

    // C/D layout: col = lane&15, row = (lane>>4)*4 + i. Rows 0..7 = speakers.
    if (lane < 32) {
        const int col = lane & 15;
        #pragma unroll
        for (int i = 0; i < 4; ++i) {
            const int srow = (lane >> 4) * 4 + i;
            pooled_p[((size_t)th * B * S + (size_t)(b * S + srow)) * FEA + f0 + wave * 16 + col]
                = acc[i];
        }
    }
}

// ---------------- Kernel B: per (b,s): denom, w, gate, e = a @ m ----------------
__global__ __launch_bounds__(256) void wattn_kernel(const float* __restrict__ pooled_p,
                                                    const float* __restrict__ mask,
                                                    const float* __restrict__ W_w,
                                                    const float* __restrict__ W_b,
                                                    const float* __restrict__ u_in,
                                                    const float* __restrict__ v_w,
                                                    const float* __restrict__ v_b,
                                                    const float* __restrict__ m,
                                                    float* __restrict__ out) {
    __shared__ float u_lds[NCL * H];   // 16 KB
    __shared__ float a_lds[NCL];
    __shared__ float red[256];
    __shared__ float wred[4][8];
    __shared__ float w_sh[H];

    const int bs  = blockIdx.x;
    const int b   = bs >> 3, s = bs & 7;
    const int tid = threadIdx.x;

    for (int i = tid; i < NCL * H; i += 256) u_lds[i] = u_in[i];

    // denom = sum_t mask[b,s,t]
    float p = 0.f;
    for (int t = tid; t < T; t += 256) p += mask[(b * S + s) * T + t];
    red[tid] = p;
    __syncthreads();
    for (int st = 128; st > 0; st >>= 1) {
        if (tid < st) red[tid] += red[tid + st];
        __syncthreads();
    }
    const float inv_d = 1.f / (red[0] + 1e-10f);

    // w[h] = (pooled[b,s,:] * inv_d) @ W_w[h,:] + W_b[h]
    float acc[8];
    #pragma unroll
    for (int h = 0; h < 8; ++h) acc[h] = 0.f;
    for (int f = tid; f < FEA; f += 256) {
        const float xv = (pooled_p[(size_t)bs * FEA + f]
                        + pooled_p[(size_t)(B * S + bs) * FEA + f]) * inv_d;
        #pragma unroll
        for (int h = 0; h < 8; ++h) acc[h] += xv * W_w[h * FEA + f];
    }
    const int lane = tid & 63, wave = tid >> 6;
    #pragma unroll
    for (int h = 0; h < 8; ++h) {
        float v = acc[h];
        #pragma unroll
        for (int off = 32; off > 0; off >>= 1) v += __shfl_xor(v, off, 64);
        if (lane == 0) wred[wave][h] = v;
    }
    __syncthreads();
    if (tid < 8)
        w_sh[tid] = wred[0][tid] + wred[1][tid] + wred[2][tid] + wred[3][tid] + W_b[tid];
    __syncthreads();

    // gate
    float vw[8];
    #pragma unroll
    for (int h = 0; h < 8; ++h) vw[h] = v_w[h];
    const float vb = v_b[0];
    for (int n = tid; n < NCL; n += 256) {
        float c = vb;
        #pragma unroll
        for (int h = 0; h < 8; ++h) c += tanhf(w_sh[h] + u_lds[n * H + h]) * vw[h];
        a_lds[n] = 1.f / (1.f + expf(-c));
    }
    __syncthreads();

    // e[emb] = sum_n a[n] * m[n, emb]
    float e = 0.f;
    #pragma unroll 4
    for (int n = 0; n < NCL; ++n) e += a_lds[n] * m[n * EMB + tid];
    out[bs * EMB + tid] = e;
}

extern "C" void kernel_launch(void* const* d_in, const int* in_sizes, int n_in,
                              void* d_out, int out_size, void* d_ws, size_t ws_size,
                              hipStream_t stream) {
    const float* x    = (const float*)d_in[0];
    const float* mask = (const float*)d_in[1];
    const float* W_w  = (const float*)d_in[2];
    const float* W_b  = (const float*)d_in[3];
    const float* U_w  = (const float*)d_in[4];
    const float* U_b  = (const float*)d_in[5];
    const float* v_w  = (const float*)d_in[6];
    const float* v_b  = (const float*)d_in[7];
    const float* m    = (const float*)d_in[8];
    float* out = (float*)d_out;

    float* ws       = (float*)d_ws;
    float* pooled_p = ws;                         // 2 * B*S*FEA floats (partials)
    float* u_buf    = ws + 2 * B * S * FEA;       // NCL*H floats

    pool_u_kernel<<<dim3(FEA / BF + 1, B, 2), 256, 0, stream>>>(
        x, mask, U_w, U_b, m, pooled_p, u_buf);
    wattn_kernel<<<B * S, 256, 0, stream>>>(
        pooled_p, mask, W_w, W_b, u_buf, v_w, v_b, m, out);
}

// Round 9
// 75.240 us; speedup vs baseline: 1.6062x; 1.2470x over previous
//
#include <hip/hip_runtime.h>
#include <hip/hip_bf16.h>
#include <math.h>

#define B 32
#define S 8
#define FEA 2560
#define T 800
#define NCL 512
#define EMB 256
#define H 8

#define BF 64            // features per block (16 per wave)
#define SEC 128          // k-floats per staged section
#define NSEC 6           // full sections (k 0..767); tail 32 via direct-global MFMA
#define XTILE 16384      // bytes per x buffer: 64 rows * 256 B
#define MROWB 1664       // bytes per mask row in LDS (1600 data + 64 pad; 13*128)

typedef __attribute__((ext_vector_type(8))) short bf16x8;
typedef __attribute__((ext_vector_type(4))) float f32x4;

__device__ __forceinline__ short4 cvt_bf16x4(float4 v) {
    union { short4 s4; __hip_bfloat162 h[2]; } u;
    u.h[0] = __float22bfloat162_rn(make_float2(v.x, v.y));
    u.h[1] = __float22bfloat162_rn(make_float2(v.z, v.w));
    return u.s4;
}

// ---------------- Kernel A: pooled via MFMA, linear-run staging + XOR-swizzled LDS ----------------
// grid (41, 32): x<40 pool tiles, x==40 & b<8 -> u blocks.
__global__ __launch_bounds__(256) void pool_u_kernel(const float* __restrict__ x,
                                                     const float* __restrict__ mask,
                                                     const float* __restrict__ U_w,
                                                     const float* __restrict__ U_b,
                                                     const float* __restrict__ m,
                                                     float* __restrict__ pooled,
                                                     float* __restrict__ u_out) {
    const int b = blockIdx.y;

    if (blockIdx.x == FEA / BF) {
        if (b >= 8) return;
        const int n  = b * 64 + (threadIdx.x >> 2);
        const int h0 = (threadIdx.x & 3) * 2;
        float a0 = 0.f, a1 = 0.f;
        #pragma unroll 4
        for (int e = 0; e < EMB; ++e) {
            const float mv = m[n * EMB + e];
            a0 += mv * U_w[h0 * EMB + e];
            a1 += mv * U_w[(h0 + 1) * EMB + e];
        }
        u_out[n * H + h0]     = a0 + U_b[h0];
        u_out[n * H + h0 + 1] = a1 + U_b[h0 + 1];
        return;
    }

    __shared__ short mask_l[S * (MROWB / 2)];   // 13312 B
    __shared__ short xls[XTILE];                // 2 buffers * 16384 B = 32768 B

    const int tid = threadIdx.x;
    const int f0  = blockIdx.x * BF;
    const float* xb = x + (size_t)b * FEA * T;

    float4 R[8];

    // ---- issue section-0 loads (8 x float4, 512 B runs: row = r*8 + tid>>5, col = tid&31) ----
    #pragma unroll
    for (int r = 0; r < 8; ++r) {
        const int row = r * 8 + (tid >> 5), c4 = tid & 31;
        R[r] = *(const float4*)(xb + (size_t)(f0 + row) * T + c4 * 4);
    }

    // ---- stage mask[b,:,:] bf16, swizzled (byte ^= (s&7)<<4 within 128B blocks) ----
    for (int v = tid; v < S * 200; v += 256) {
        const int s = v / 200, c4 = v % 200;
        const float4 mv = *(const float4*)(mask + ((size_t)(b * S + s)) * T + c4 * 4);
        const int byte = s * MROWB + ((c4 * 8) ^ (s << 4));
        *(short4*)((char*)mask_l + byte) = cvt_bf16x4(mv);
    }

    // ---- write section 0 -> buf0, issue section-1 loads ----
    #pragma unroll
    for (int r = 0; r < 8; ++r) {
        const int row = r * 8 + (tid >> 5), c4 = tid & 31;
        *(short4*)((char*)xls + row * 256 + ((c4 * 8) ^ ((row & 7) << 4))) = cvt_bf16x4(R[r]);
    }
    #pragma unroll
    for (int r = 0; r < 8; ++r) {
        const int row = r * 8 + (tid >> 5), c4 = tid & 31;
        R[r] = *(const float4*)(xb + (size_t)(f0 + row) * T + SEC + c4 * 4);
    }
    __syncthreads();

    const int wave = tid >> 6, lane = tid & 63;
    const int kb16 = (lane >> 4) * 16;
    const int xrow = wave * 16 + (lane & 15);
    const int xswz = (xrow & 7) << 4;
    const int srow = (lane & 15) & 7;
    const int mbase = srow * MROWB;
    const int mswz = srow << 4;

    f32x4 acc = {0.f, 0.f, 0.f, 0.f};

    #pragma unroll
    for (int sec = 0; sec < NSEC; ++sec) {
        const int bufb = (sec & 1) * XTILE;
        // compute section (K=128 -> 4 MFMA steps)
        #pragma unroll
        for (int st = 0; st < 4; ++st) {
            const int xb_ = bufb + xrow * 256 + ((st * 64 + kb16) ^ xswz);
            const bf16x8 bx = *(const bf16x8*)((const char*)xls + xb_);
            const int mb_ = mbase + (((sec * 4 + st) * 64 + kb16) ^ mswz);
            const bf16x8 am = *(const bf16x8*)((const char*)mask_l + mb_);
            acc = __builtin_amdgcn_mfma_f32_16x16x32_bf16(am, bx, acc, 0, 0, 0);
        }
        if (sec < NSEC - 1) {
            // write section sec+1 -> other buffer (readers of it finished last iteration)
            const int wb = ((sec + 1) & 1) * XTILE;
            #pragma unroll
            for (int r = 0; r < 8; ++r) {
                const int row = r * 8 + (tid >> 5), c4 = tid & 31;
                *(short4*)((char*)xls + wb + row * 256 + ((c4 * 8) ^ ((row & 7) << 4)))
                    = cvt_bf16x4(R[r]);
            }
            if (sec < NSEC - 2) {   // issue section sec+2 loads (consumed next iteration)
                #pragma unroll
                for (int r = 0; r < 8; ++r) {
                    const int row = r * 8 + (tid >> 5), c4 = tid & 31;
                    R[r] = *(const float4*)(xb + (size_t)(f0 + row) * T + (sec + 2) * SEC + c4 * 4);
                }
            }
        }
        __syncthreads();
    }

    // ---- tail: k 768..799, x direct from global, mask from LDS (stGlobal = 24) ----
    {
        const float* xt = xb + (size_t)(f0 + xrow) * T + 768 + (lane >> 4) * 8;
        const float4 t0 = *(const float4*)(xt);
        const float4 t1 = *(const float4*)(xt + 4);
        union { bf16x8 v; short4 s4[2]; } Bx;
        Bx.s4[0] = cvt_bf16x4(t0);
        Bx.s4[1] = cvt_bf16x4(t1);
        const int mb_ = mbase + ((24 * 64 + kb16) ^ mswz);
        const bf16x8 am = *(const bf16x8*)((const char*)mask_l + mb_);
        acc = __builtin_amdgcn_mfma_f32_16x16x32_bf16(am, Bx.v, acc, 0, 0, 0);
    }

    // C/D layout: col = lane&15, row = (lane>>4)*4 + i. Rows 0..7 = speakers.
    if (lane < 32) {
        const int col = lane & 15;
        #pragma unroll
        for (int i = 0; i < 4; ++i) {
            const int sr = (lane >> 4) * 4 + i;
            pooled[(size_t)(b * S + sr) * FEA + f0 + wave * 16 + col] = acc[i];
        }
    }
}

// ---------------- Kernel B1: per (b,s) denom + w ----------------
__global__ __launch_bounds__(256) void wden_kernel(const float* __restrict__ pooled,
                                                   const float* __restrict__ mask,
                                                   const float* __restrict__ W_w,
                                                   const float* __restrict__ W_b,
                                                   float* __restrict__ w_out) {
    __shared__ float red[256];
    __shared__ float wred[4][8];
    const int bs  = blockIdx.x;
    const int tid = threadIdx.x;

    float p = 0.f;
    for (int t = tid; t < T; t += 256) p += mask[(size_t)bs * T + t];
    red[tid] = p;
    __syncthreads();
    for (int st = 128; st > 0; st >>= 1) {
        if (tid < st) red[tid] += red[tid + st];
        __syncthreads();
    }
    const float inv_d = 1.f / (red[0] + 1e-10f);

    float acc[8];
    #pragma unroll
    for (int h = 0; h < 8; ++h) acc[h] = 0.f;
    for (int f = tid; f < FEA; f += 256) {
        const float xv = pooled[(size_t)bs * FEA + f] * inv_d;
        #pragma unroll
        for (int h = 0; h < 8; ++h) acc[h] += xv * W_w[h * FEA + f];
    }
    const int lane = tid & 63, wave = tid >> 6;
    #pragma unroll
    for (int h = 0; h < 8; ++h) {
        float v = acc[h];
        #pragma unroll
        for (int off = 32; off > 0; off >>= 1) v += __shfl_xor(v, off, 64);
        if (lane == 0) wred[wave][h] = v;
    }
    __syncthreads();
    if (tid < 8)
        w_out[bs * H + tid] = wred[0][tid] + wred[1][tid] + wred[2][tid] + wred[3][tid] + W_b[tid];
}

// ---------------- Kernel B2: gate a[bs,n] (+ zero out) ----------------
__global__ __launch_bounds__(256) void gate_kernel(const float* __restrict__ w_buf,
                                                   const float* __restrict__ u_buf,
                                                   const float* __restrict__ v_w,
                                                   const float* __restrict__ v_b,
                                                   float* __restrict__ a_out,
                                                   float* __restrict__ out) {
    const int idx = blockIdx.x * 256 + threadIdx.x;   // 0..131071
    if (idx < B * S * EMB) out[idx] = 0.f;
    const int bs = idx >> 9, n = idx & 511;
    float c = v_b[0];
    #pragma unroll
    for (int h = 0; h < 8; ++h)
        c += tanhf(w_buf[bs * H + h] + u_buf[n * H + h]) * v_w[h];
    a_out[idx] = 1.f / (1.f + expf(-c));
}

// ---------------- Kernel B3: e = a @ m (n-split, atomic accumulate) ----------------
__global__ __launch_bounds__(256) void egemv_kernel(const float* __restrict__ a_buf,
                                                    const float* __restrict__ m,
                                                    float* __restrict__ out) {
    __shared__ float a_sh[256];
    const int bs = blockIdx.x >> 1, half = blockIdx.x & 1;
    const int tid = threadIdx.x;
    a_sh[tid] = a_buf[bs * NCL + half * 256 + tid];
    __syncthreads();
    float acc = 0.f;
    #pragma unroll 8
    for (int n = 0; n < 256; ++n)
        acc += a_sh[n] * m[(half * 256 + n) * EMB + tid];
    atomicAdd(&out[bs * EMB + tid], acc);
}

extern "C" void kernel_launch(void* const* d_in, const int* in_sizes, int n_in,
                              void* d_out, int out_size, void* d_ws, size_t ws_size,
                              hipStream_t stream) {
    const float* x    = (const float*)d_in[0];
    const float* mask = (const float*)d_in[1];
    const float* W_w  = (const float*)d_in[2];
    const float* W_b  = (const float*)d_in[3];
    const float* U_w  = (const float*)d_in[4];
    const float* U_b  = (const float*)d_in[5];
    const float* v_w  = (const float*)d_in[6];
    const float* v_b  = (const float*)d_in[7];
    const float* m    = (const float*)d_in[8];
    float* out = (float*)d_out;

    float* ws     = (float*)d_ws;
    float* pooled = ws;                          // B*S*FEA
    float* u_buf  = pooled + B * S * FEA;        // NCL*H
    float* w_buf  = u_buf + NCL * H;             // B*S*H
    float* a_buf  = w_buf + B * S * H;           // B*S*NCL

    pool_u_kernel<<<dim3(FEA / BF + 1, B), 256, 0, stream>>>(
        x, mask, U_w, U_b, m, pooled, u_buf);
    wden_kernel<<<B * S, 256, 0, stream>>>(pooled, mask, W_w, W_b, w_buf);
    gate_kernel<<<B * S * NCL / 256, 256, 0, stream>>>(w_buf, u_buf, v_w, v_b, a_buf, out);
    egemv_kernel<<<B * S * 2, 256, 0, stream>>>(a_buf, m, out);
}

// Round 10
// 75.132 us; speedup vs baseline: 1.6085x; 1.0014x over previous
//
#include <hip/hip_runtime.h>
#include <hip/hip_bf16.h>
#include <math.h>

#define B 32
#define S 8
#define FEA 2560
#define T 800
#define NCL 512
#define EMB 256
#define H 8

#define BF 64            // features per block (16 per wave)
#define SEC 128          // k-floats per staged section
#define NSEC 6           // full sections (k 0..767); tail 32 via direct-global MFMA
#define WVB 4096         // bytes per wave x-buffer: 16 rows * 256 B
#define MROWB 1664       // bytes per mask row in LDS (1600 data + 64 pad)

typedef __attribute__((ext_vector_type(8))) short bf16x8;
typedef __attribute__((ext_vector_type(4))) float f32x4;

__device__ __forceinline__ short4 cvt_bf16x4(float4 v) {
    union { short4 s4; __hip_bfloat162 h[2]; } u;
    u.h[0] = __float22bfloat162_rn(make_float2(v.x, v.y));
    u.h[1] = __float22bfloat162_rn(make_float2(v.z, v.w));
    return u.s4;
}

// ---- wave-private staging: 16 rows x 128 k per section; 2 rows x 512 B runs per instr ----
__device__ __forceinline__ void load_sec_w(const float* __restrict__ xw, int sec,
                                           int lane, float4 R[8]) {
    const int c4 = lane & 31;
    #pragma unroll
    for (int r = 0; r < 8; ++r) {
        const int row = r * 2 + (lane >> 5);
        R[r] = *(const float4*)(xw + (size_t)row * T + sec * SEC + c4 * 4);
    }
}

__device__ __forceinline__ void write_sec_w(char* __restrict__ buf, int lane, const float4 R[8]) {
    const int c4 = lane & 31;
    #pragma unroll
    for (int r = 0; r < 8; ++r) {
        const int row = r * 2 + (lane >> 5);
        *(short4*)(buf + row * 256 + ((c4 * 8) ^ ((row & 7) << 4))) = cvt_bf16x4(R[r]);
    }
}

// 4 MFMA steps over one staged section (K=128)
#define STEP4(secv, bufp) {                                                          \
    _Pragma("unroll")                                                                \
    for (int st_ = 0; st_ < 4; ++st_) {                                              \
        const bf16x8 bx_ = *(const bf16x8*)((bufp) + xrow * 256                      \
                              + ((st_ * 64 + kb16) ^ xswz));                         \
        const bf16x8 am_ = *(const bf16x8*)((const char*)mask_l + mbase              \
                              + ((((secv) * 4 + st_) * 64 + kb16) ^ mswz));          \
        acc = __builtin_amdgcn_mfma_f32_16x16x32_bf16(am_, bx_, acc, 0, 0, 0);       \
    }                                                                                \
}

// ---------------- Kernel A: pooled via MFMA, wave-private barrier-free + linear runs ----------------
// grid (41, 32): x<40 pool tiles, x==40 & b<8 -> u blocks.
__global__ __launch_bounds__(256) void pool_u_kernel(const float* __restrict__ x,
                                                     const float* __restrict__ mask,
                                                     const float* __restrict__ U_w,
                                                     const float* __restrict__ U_b,
                                                     const float* __restrict__ m,
                                                     float* __restrict__ pooled,
                                                     float* __restrict__ u_out) {
    const int b = blockIdx.y;

    if (blockIdx.x == FEA / BF) {
        if (b >= 8) return;
        const int n  = b * 64 + (threadIdx.x >> 2);
        const int h0 = (threadIdx.x & 3) * 2;
        float a0 = 0.f, a1 = 0.f;
        #pragma unroll 4
        for (int e = 0; e < EMB; ++e) {
            const float mv = m[n * EMB + e];
            a0 += mv * U_w[h0 * EMB + e];
            a1 += mv * U_w[(h0 + 1) * EMB + e];
        }
        u_out[n * H + h0]     = a0 + U_b[h0];
        u_out[n * H + h0 + 1] = a1 + U_b[h0 + 1];
        return;
    }

    __shared__ short mask_l[S * (MROWB / 2)];   // 13312 B, shared, read-only after barrier
    __shared__ char  xls[4 * 2 * WVB];          // 32768 B, wave-private double buffers

    const int tid  = threadIdx.x;
    const int wave = tid >> 6, lane = tid & 63;
    const int f0   = blockIdx.x * BF;

    const float* xw = x + ((size_t)b * FEA + f0 + wave * 16) * T;
    char* buf0 = xls + wave * 2 * WVB;
    char* buf1 = buf0 + WVB;

    float4 R0[8], R1[8];

    // ---- prologue: issue sections 0,1; stage mask while they fly ----
    load_sec_w(xw, 0, lane, R0);
    load_sec_w(xw, 1, lane, R1);

    for (int v = tid; v < S * 200; v += 256) {
        const int s = v / 200, c4 = v % 200;
        const float4 mv = *(const float4*)(mask + ((size_t)(b * S + s)) * T + c4 * 4);
        const int byte = s * MROWB + ((c4 * 8) ^ (s << 4));
        *(short4*)((char*)mask_l + byte) = cvt_bf16x4(mv);
    }
    __syncthreads();      // the ONLY barrier: mask_l visible to all waves

    write_sec_w(buf0, lane, R0);          // sec 0 -> buf0
    load_sec_w(xw, 2, lane, R0);
    write_sec_w(buf1, lane, R1);          // sec 1 -> buf1
    load_sec_w(xw, 3, lane, R1);

    const int kb16 = (lane >> 4) * 16;
    const int xrow = lane & 15;           // feature col within wave tile
    const int xswz = (xrow & 7) << 4;
    const int srow = lane & 7;
    const int mbase = srow * MROWB;
    const int mswz = srow << 4;

    f32x4 acc = {0.f, 0.f, 0.f, 0.f};

    // ---- main loop: barrier-free depth-2; writes lag their loads by a full iteration ----
    #pragma unroll 1
    for (int st = 0; st < 4; st += 2) {
        STEP4(st, buf0)
        write_sec_w(buf0, lane, R0);              // sec st+2 (R0 loaded last iter)
        if (st + 4 < NSEC) load_sec_w(xw, st + 4, lane, R0);
        STEP4(st + 1, buf1)
        write_sec_w(buf1, lane, R1);              // sec st+3
        if (st + 5 < NSEC) load_sec_w(xw, st + 5, lane, R1);
    }
    // ---- epilogue: buf0 = sec4, buf1 = sec5 ----
    STEP4(4, buf0)
    STEP4(5, buf1)

    // ---- tail: k 768..799, x direct from global, mask from LDS (gstep = 24) ----
    {
        const float* xt = xw + (size_t)xrow * T + 768 + (lane >> 4) * 8;
        const float4 t0 = *(const float4*)(xt);
        const float4 t1 = *(const float4*)(xt + 4);
        union { bf16x8 v; short4 s4[2]; } Bx;
        Bx.s4[0] = cvt_bf16x4(t0);
        Bx.s4[1] = cvt_bf16x4(t1);
        const bf16x8 am = *(const bf16x8*)((const char*)mask_l + mbase
                              + ((24 * 64 + kb16) ^ mswz));
        acc = __builtin_amdgcn_mfma_f32_16x16x32_bf16(am, Bx.v, acc, 0, 0, 0);
    }

    // C/D layout: col = lane&15, row = (lane>>4)*4 + i. Rows 0..7 = speakers.
    if (lane < 32) {
        const int col = lane & 15;
        #pragma unroll
        for (int i = 0; i < 4; ++i) {
            const int sr = (lane >> 4) * 4 + i;
            pooled[(size_t)(b * S + sr) * FEA + f0 + wave * 16 + col] = acc[i];
        }
    }
}

// ---------------- Kernel B1: per (b,s) denom + w ----------------
__global__ __launch_bounds__(256) void wden_kernel(const float* __restrict__ pooled,
                                                   const float* __restrict__ mask,
                                                   const float* __restrict__ W_w,
                                                   const float* __restrict__ W_b,
                                                   float* __restrict__ w_out) {
    __shared__ float red[256];
    __shared__ float wred[4][8];
    const int bs  = blockIdx.x;
    const int tid = threadIdx.x;

    float p = 0.f;
    for (int t = tid; t < T; t += 256) p += mask[(size_t)bs * T + t];
    red[tid] = p;
    __syncthreads();
    for (int st = 128; st > 0; st >>= 1) {
        if (tid < st) red[tid] += red[tid + st];
        __syncthreads();
    }
    const float inv_d = 1.f / (red[0] + 1e-10f);

    float acc[8];
    #pragma unroll
    for (int h = 0; h < 8; ++h) acc[h] = 0.f;
    for (int f = tid; f < FEA; f += 256) {
        const float xv = pooled[(size_t)bs * FEA + f] * inv_d;
        #pragma unroll
        for (int h = 0; h < 8; ++h) acc[h] += xv * W_w[h * FEA + f];
    }
    const int lane = tid & 63, wave = tid >> 6;
    #pragma unroll
    for (int h = 0; h < 8; ++h) {
        float v = acc[h];
        #pragma unroll
        for (int off = 32; off > 0; off >>= 1) v += __shfl_xor(v, off, 64);
        if (lane == 0) wred[wave][h] = v;
    }
    __syncthreads();
    if (tid < 8)
        w_out[bs * H + tid] = wred[0][tid] + wred[1][tid] + wred[2][tid] + wred[3][tid] + W_b[tid];
}

// ---------------- Kernel B2: gate a[bs,n] (+ zero out) ----------------
__global__ __launch_bounds__(256) void gate_kernel(const float* __restrict__ w_buf,
                                                   const float* __restrict__ u_buf,
                                                   const float* __restrict__ v_w,
                                                   const float* __restrict__ v_b,
                                                   float* __restrict__ a_out,
                                                   float* __restrict__ out) {
    const int idx = blockIdx.x * 256 + threadIdx.x;   // 0..131071
    if (idx < B * S * EMB) out[idx] = 0.f;
    const int bs = idx >> 9, n = idx & 511;
    float c = v_b[0];
    #pragma unroll
    for (int h = 0; h < 8; ++h)
        c += tanhf(w_buf[bs * H + h] + u_buf[n * H + h]) * v_w[h];
    a_out[idx] = 1.f / (1.f + expf(-c));
}

// ---------------- Kernel B3: e = a @ m (n-split, atomic accumulate) ----------------
__global__ __launch_bounds__(256) void egemv_kernel(const float* __restrict__ a_buf,
                                                    const float* __restrict__ m,
                                                    float* __restrict__ out) {
    __shared__ float a_sh[256];
    const int bs = blockIdx.x >> 1, half = blockIdx.x & 1;
    const int tid = threadIdx.x;
    a_sh[tid] = a_buf[bs * NCL + half * 256 + tid];
    __syncthreads();
    float acc = 0.f;
    #pragma unroll 8
    for (int n = 0; n < 256; ++n)
        acc += a_sh[n] * m[(half * 256 + n) * EMB + tid];
    atomicAdd(&out[bs * EMB + tid], acc);
}

extern "C" void kernel_launch(void* const* d_in, const int* in_sizes, int n_in,
                              void* d_out, int out_size, void* d_ws, size_t ws_size,
                              hipStream_t stream) {
    const float* x    = (const float*)d_in[0];
    const float* mask = (const float*)d_in[1];
    const float* W_w  = (const float*)d_in[2];
    const float* W_b  = (const float*)d_in[3];
    const float* U_w  = (const float*)d_in[4];
    const float* U_b  = (const float*)d_in[5];
    const float* v_w  = (const float*)d_in[6];
    const float* v_b  = (const float*)d_in[7];
    const float* m    = (const float*)d_in[8];
    float* out = (float*)d_out;

    float* ws     = (float*)d_ws;
    float* pooled = ws;                          // B*S*FEA
    float* u_buf  = pooled + B * S * FEA;        // NCL*H
    float* w_buf  = u_buf + NCL * H;             // B*S*H
    float* a_buf  = w_buf + B * S * H;           // B*S*NCL

    pool_u_kernel<<<dim3(FEA / BF + 1, B), 256, 0, stream>>>(
        x, mask, U_w, U_b, m, pooled, u_buf);
    wden_kernel<<<B * S, 256, 0, stream>>>(pooled, mask, W_w, W_b, w_buf);
    gate_kernel<<<B * S * NCL / 256, 256, 0, stream>>>(w_buf, u_buf, v_w, v_b, a_buf, out);
    egemv_kernel<<<B * S * 2, 256, 0, stream>>>(a_buf, m, out);
}